// Round 1
// baseline (527.739 us; speedup 1.0000x reference)
//
#include <hip/hip_runtime.h>
#include <math.h>

#define NPTS 8192
#define KNN  20

// ---------------- KNN: top-20 nearest (excl. self) ----------------
// grid 256 blocks; block 256 = 8 splits x 32 queries.
// Per-thread top-20 kept in LDS (dynamic index -> LDS, not scratch).
__global__ __launch_bounds__(256) void knn_kernel(const float* __restrict__ x,
                                                  int* __restrict__ idx_out) {
    __shared__ float lds_d[KNN][256];
    __shared__ int   lds_i[KNN][256];
    const int t = threadIdx.x;
    const int q = t & 31;        // query slot in block
    const int split = t >> 5;    // 0..7
    const int i = blockIdx.x * 32 + q;

    const float xi0 = x[3*i+0], xi1 = x[3*i+1], xi2 = x[3*i+2];
    const float sqi = xi0*xi0 + xi1*xi1 + xi2*xi2;

#pragma unroll
    for (int s = 0; s < KNN; ++s) { lds_d[s][t] = INFINITY; lds_i[s][t] = -1; }
    float curmax = INFINITY;
    int   maxpos = 0;

    const int j0 = split * (NPTS / 8);
#pragma unroll 4
    for (int jj = 0; jj < NPTS / 8; ++jj) {
        const int j = j0 + jj;
        const float xj0 = x[3*j+0], xj1 = x[3*j+1], xj2 = x[3*j+2];
        const float sqj = xj0*xj0 + xj1*xj1 + xj2*xj2;
        const float dot = xi0*xj0 + xi1*xj1 + xi2*xj2;
        float d = sqi + sqj - 2.0f * dot;
        if (j == i) d = INFINITY;
        if (d < curmax) {
            lds_d[maxpos][t] = d;
            lds_i[maxpos][t] = j;
            curmax = lds_d[0][t]; maxpos = 0;
#pragma unroll
            for (int s = 1; s < KNN; ++s) {
                float v = lds_d[s][t];
                if (v > curmax) { curmax = v; maxpos = s; }
            }
        }
    }
    __syncthreads();
    if (t < 32) {
        // continue the replace-max scan over the other 7 splits' lists
        for (int s = 1; s < 8; ++s) {
            const int src = s * 32 + t;
#pragma unroll
            for (int e = 0; e < KNN; ++e) {
                const float d = lds_d[e][src];
                const int   j = lds_i[e][src];
                if (d < curmax) {
                    lds_d[maxpos][t] = d;
                    lds_i[maxpos][t] = j;
                    curmax = lds_d[0][t]; maxpos = 0;
#pragma unroll
                    for (int s2 = 1; s2 < KNN; ++s2) {
                        float v = lds_d[s2][t];
                        if (v > curmax) { curmax = v; maxpos = s2; }
                    }
                }
            }
        }
#pragma unroll
        for (int e = 0; e < KNN; ++e) idx_out[i*KNN + e] = lds_i[e][t];
    }
}

// ---------------- weight prep: Wc = [Wa - Wb ; Wb], rows x C ----------------
__global__ void prep_w(const float* __restrict__ W, float* __restrict__ Wc,
                       int O, int C) {
    const int tid = blockIdx.x * blockDim.x + threadIdx.x;
    if (tid >= O * C) return;
    const int o = tid / C, k = tid % C;
    const float wa = W[o*2*C + k];
    const float wb = W[o*2*C + C + k];
    Wc[o*C + k]       = wa - wb;   // base part
    Wc[(O + o)*C + k] = wb;        // u part
}

// ---------------- layer0 GEMM: K=3 special case ----------------
// T[n][m] = sum_k x[n][k] * Wc0[m][k], m < 128
__global__ __launch_bounds__(128) void gemm0_kernel(const float* __restrict__ x,
                                                    const float* __restrict__ Wc,
                                                    float* __restrict__ T) {
    __shared__ float sw[384];
    const int t = threadIdx.x;
    sw[t]       = Wc[t];
    sw[t + 128] = Wc[t + 128];
    sw[t + 256] = Wc[t + 256];
    __syncthreads();
    const int n = blockIdx.x;
    const float x0 = x[3*n+0], x1 = x[3*n+1], x2 = x[3*n+2];
    T[n*128 + t] = x0*sw[3*t+0] + x1*sw[3*t+1] + x2*sw[3*t+2];
}

// ---------------- generic fp32 GEMM: T = H (NxK) * Wc^T (MxK) ----------------
// 64x64 tile, 256 threads, 4x4 per thread. K % 16 == 0.
__global__ __launch_bounds__(256) void gemm_nt(const float* __restrict__ H,
                                               const float* __restrict__ W,
                                               float* __restrict__ T,
                                               int Kk, int Mm) {
    __shared__ float sH[64][17];
    __shared__ float sW[64][17];
    const int tx = threadIdx.x & 15;
    const int ty = threadIdx.x >> 4;
    const int row0 = blockIdx.x * 64;
    const int col0 = blockIdx.y * 64;
    float acc[4][4] = {{0.f}};
    const int l  = threadIdx.x * 4;
    const int lr = l >> 4;       // 0..63
    const int lc = l & 15;       // 0,4,8,12

    for (int k0 = 0; k0 < Kk; k0 += 16) {
        const float4 hv = *reinterpret_cast<const float4*>(&H[(row0+lr)*Kk + k0 + lc]);
        const float4 wv = *reinterpret_cast<const float4*>(&W[(col0+lr)*Kk + k0 + lc]);
        __syncthreads();   // protect previous iter's reads
        sH[lr][lc+0] = hv.x; sH[lr][lc+1] = hv.y; sH[lr][lc+2] = hv.z; sH[lr][lc+3] = hv.w;
        sW[lr][lc+0] = wv.x; sW[lr][lc+1] = wv.y; sW[lr][lc+2] = wv.z; sW[lr][lc+3] = wv.w;
        __syncthreads();
#pragma unroll
        for (int kk = 0; kk < 16; ++kk) {
            float a0 = sH[ty*4+0][kk], a1 = sH[ty*4+1][kk];
            float a2 = sH[ty*4+2][kk], a3 = sH[ty*4+3][kk];
            float b0 = sW[tx*4+0][kk], b1 = sW[tx*4+1][kk];
            float b2 = sW[tx*4+2][kk], b3 = sW[tx*4+3][kk];
            acc[0][0] += a0*b0; acc[0][1] += a0*b1; acc[0][2] += a0*b2; acc[0][3] += a0*b3;
            acc[1][0] += a1*b0; acc[1][1] += a1*b1; acc[1][2] += a1*b2; acc[1][3] += a1*b3;
            acc[2][0] += a2*b0; acc[2][1] += a2*b1; acc[2][2] += a2*b2; acc[2][3] += a2*b3;
            acc[3][0] += a3*b0; acc[3][1] += a3*b1; acc[3][2] += a3*b2; acc[3][3] += a3*b3;
        }
    }
#pragma unroll
    for (int r = 0; r < 4; ++r)
#pragma unroll
        for (int c = 0; c < 4; ++c)
            T[(row0 + ty*4 + r)*Mm + col0 + tx*4 + c] = acc[r][c];
}

// ---------------- gather + max + bias + relu ----------------
// out[i][o] = relu( T[i][o] + b[o] + max_k T[idx[i,k]][O+o] ), block = O threads
__global__ void maxrelu_kernel(const float* __restrict__ T, const int* __restrict__ idx,
                               const float* __restrict__ bias, float* __restrict__ out,
                               int O) {
    const int i = blockIdx.x;
    const int o = threadIdx.x;
    const int M2 = 2 * O;
    __shared__ int sidx[KNN];
    if (o < KNN) sidx[o] = idx[i*KNN + o];
    __syncthreads();
    float m = -INFINITY;
#pragma unroll
    for (int k = 0; k < KNN; ++k) {
        m = fmaxf(m, T[sidx[k]*M2 + O + o]);
    }
    const float base = T[i*M2 + o] + bias[o];
    out[i*O + o] = fmaxf(base + m, 0.0f);
}

extern "C" void kernel_launch(void* const* d_in, const int* in_sizes, int n_in,
                              void* d_out, int out_size, void* d_ws, size_t ws_size,
                              hipStream_t stream) {
    const float* x  = (const float*)d_in[0];
    const float* W0 = (const float*)d_in[1];
    const float* b0 = (const float*)d_in[2];
    const float* W1 = (const float*)d_in[3];
    const float* b1 = (const float*)d_in[4];
    const float* W2 = (const float*)d_in[5];
    const float* b2 = (const float*)d_in[6];
    float* out = (float*)d_out;
    char*  ws  = (char*)d_ws;

    // workspace layout (16B aligned offsets), total ~21 MB
    int*   idx  = (int*)(ws + 0);                 // 8192*20*4   = 655360
    float* Wc0  = (float*)(ws + 655360);          // 384*4       = 1536
    float* Wc1  = (float*)(ws + 656896);          // 16384*4     = 65536
    float* Wc2  = (float*)(ws + 722432);          // 65536*4     = 262144
    float* bufA = (float*)(ws + 984576);          // 8192*512*4  = 16777216
    float* bufB = (float*)(ws + 17761792);        // 8192*128*4  = 4194304

    // KNN graph (shared by all 3 layers)
    knn_kernel<<<256, 256, 0, stream>>>(x, idx);

    // weight restructure: Wc = [Wa - Wb ; Wb]
    prep_w<<<1, 256, 0, stream>>>(W0, Wc0, 64, 3);
    prep_w<<<32, 256, 0, stream>>>(W1, Wc1, 128, 64);
    prep_w<<<128, 256, 0, stream>>>(W2, Wc2, 256, 128);

    // layer 0: x(8192x3) -> t0(8192x128) -> h0(8192x64)
    gemm0_kernel<<<NPTS, 128, 0, stream>>>(x, Wc0, bufA);
    maxrelu_kernel<<<NPTS, 64, 0, stream>>>(bufA, idx, b0, bufB, 64);

    // layer 1: h0(8192x64) -> t1(8192x256) -> h1(8192x128)
    gemm_nt<<<dim3(128, 4), 256, 0, stream>>>(bufB, Wc1, bufA, 64, 256);
    maxrelu_kernel<<<NPTS, 128, 0, stream>>>(bufA, idx, b1, bufB, 128);

    // layer 2: h1(8192x128) -> t2(8192x512) -> out(8192x256)
    gemm_nt<<<dim3(128, 8), 256, 0, stream>>>(bufB, Wc2, bufA, 128, 512);
    maxrelu_kernel<<<NPTS, 256, 0, stream>>>(bufA, idx, b2, out, 256);
}

// Round 2
// 394.422 us; speedup vs baseline: 1.3380x; 1.3380x over previous
//
#include <hip/hip_runtime.h>
#include <math.h>

#define NPTS 8192
#define KNN  20
#define QPB  8     // queries per block
#define SPL  32    // candidate splits per query
#define CPL  (NPTS / SPL)   // candidates per lane = 256

// ---------------- preprocess: xq[i] = (x,y,z, |x|^2) ----------------
__global__ void prep_xq(const float* __restrict__ x, float4* __restrict__ xq) {
    const int i = blockIdx.x * 256 + threadIdx.x;
    if (i < NPTS) {
        const float a = x[3*i+0], b = x[3*i+1], c = x[3*i+2];
        xq[i] = make_float4(a, b, c, a*a + b*b + c*c);
    }
}

// ---------------- KNN: top-20 nearest (excl. self) ----------------
// grid 1024 blocks; block 256 threads = 32 splits x 8 queries.
// t = split*8 + q  (8 adjacent lanes share candidate j -> broadcast load).
// Per-thread top-20 replace-max list in LDS.
__global__ __launch_bounds__(256) void knn_kernel(const float4* __restrict__ xq,
                                                  int* __restrict__ idx_out) {
    __shared__ float lds_d[KNN][256];
    __shared__ int   lds_i[KNN][256];
    const int t = threadIdx.x;
    const int q = t & (QPB - 1);
    const int split = t >> 3;
    const int i = blockIdx.x * QPB + q;

    const float4 pi = xq[i];

#pragma unroll
    for (int s = 0; s < KNN; ++s) { lds_d[s][t] = INFINITY; lds_i[s][t] = -1; }
    float curmax = INFINITY;
    int   maxpos = 0;

    const int j0 = split * CPL;
#pragma unroll 2
    for (int jj = 0; jj < CPL; ++jj) {
        const int j = j0 + jj;
        const float4 pj = xq[j];
        const float dot = pi.x*pj.x + pi.y*pj.y + pi.z*pj.z;
        float d = fmaf(-2.0f, dot, pi.w + pj.w);
        if (j == i) d = INFINITY;
        if (d < curmax) {
            lds_d[maxpos][t] = d;
            lds_i[maxpos][t] = j;
            curmax = lds_d[0][t]; maxpos = 0;
#pragma unroll
            for (int s = 1; s < KNN; ++s) {
                const float v = lds_d[s][t];
                if (v > curmax) { curmax = v; maxpos = s; }
            }
        }
    }
    __syncthreads();
    if (t < QPB) {
        // merge the other 31 splits' lists into this thread's list (column t)
        for (int s = 1; s < SPL; ++s) {
            const int src = s * QPB + t;
#pragma unroll
            for (int e = 0; e < KNN; ++e) {
                const float d = lds_d[e][src];
                const int   j = lds_i[e][src];
                if (d < curmax) {
                    lds_d[maxpos][t] = d;
                    lds_i[maxpos][t] = j;
                    curmax = lds_d[0][t]; maxpos = 0;
#pragma unroll
                    for (int s2 = 1; s2 < KNN; ++s2) {
                        const float v = lds_d[s2][t];
                        if (v > curmax) { curmax = v; maxpos = s2; }
                    }
                }
            }
        }
#pragma unroll
        for (int e = 0; e < KNN; ++e) idx_out[i*KNN + e] = lds_i[e][t];
    }
}

// ---------------- weight prep: Wc = [Wa - Wb ; Wb], rows x C ----------------
__global__ void prep_w(const float* __restrict__ W, float* __restrict__ Wc,
                       int O, int C) {
    const int tid = blockIdx.x * blockDim.x + threadIdx.x;
    if (tid >= O * C) return;
    const int o = tid / C, k = tid % C;
    const float wa = W[o*2*C + k];
    const float wb = W[o*2*C + C + k];
    Wc[o*C + k]       = wa - wb;   // base part
    Wc[(O + o)*C + k] = wb;        // u part
}

// ---------------- layer0 GEMM: K=3 special case ----------------
__global__ __launch_bounds__(128) void gemm0_kernel(const float* __restrict__ x,
                                                    const float* __restrict__ Wc,
                                                    float* __restrict__ T) {
    __shared__ float sw[384];
    const int t = threadIdx.x;
    sw[t]       = Wc[t];
    sw[t + 128] = Wc[t + 128];
    sw[t + 256] = Wc[t + 256];
    __syncthreads();
    const int n = blockIdx.x;
    const float x0 = x[3*n+0], x1 = x[3*n+1], x2 = x[3*n+2];
    T[n*128 + t] = x0*sw[3*t+0] + x1*sw[3*t+1] + x2*sw[3*t+2];
}

// ---------------- generic fp32 GEMM: T = H (NxK) * Wc^T (MxK) ----------------
// 64x64 tile, 256 threads, 4x4 per thread. K % 16 == 0.
__global__ __launch_bounds__(256) void gemm_nt(const float* __restrict__ H,
                                               const float* __restrict__ W,
                                               float* __restrict__ T,
                                               int Kk, int Mm) {
    __shared__ float sH[64][17];
    __shared__ float sW[64][17];
    const int tx = threadIdx.x & 15;
    const int ty = threadIdx.x >> 4;
    const int row0 = blockIdx.x * 64;
    const int col0 = blockIdx.y * 64;
    float acc[4][4] = {{0.f}};
    const int l  = threadIdx.x * 4;
    const int lr = l >> 4;       // 0..63
    const int lc = l & 15;       // 0,4,8,12

    for (int k0 = 0; k0 < Kk; k0 += 16) {
        const float4 hv = *reinterpret_cast<const float4*>(&H[(row0+lr)*Kk + k0 + lc]);
        const float4 wv = *reinterpret_cast<const float4*>(&W[(col0+lr)*Kk + k0 + lc]);
        __syncthreads();   // protect previous iter's reads
        sH[lr][lc+0] = hv.x; sH[lr][lc+1] = hv.y; sH[lr][lc+2] = hv.z; sH[lr][lc+3] = hv.w;
        sW[lr][lc+0] = wv.x; sW[lr][lc+1] = wv.y; sW[lr][lc+2] = wv.z; sW[lr][lc+3] = wv.w;
        __syncthreads();
#pragma unroll
        for (int kk = 0; kk < 16; ++kk) {
            float a0 = sH[ty*4+0][kk], a1 = sH[ty*4+1][kk];
            float a2 = sH[ty*4+2][kk], a3 = sH[ty*4+3][kk];
            float b0 = sW[tx*4+0][kk], b1 = sW[tx*4+1][kk];
            float b2 = sW[tx*4+2][kk], b3 = sW[tx*4+3][kk];
            acc[0][0] += a0*b0; acc[0][1] += a0*b1; acc[0][2] += a0*b2; acc[0][3] += a0*b3;
            acc[1][0] += a1*b0; acc[1][1] += a1*b1; acc[1][2] += a1*b2; acc[1][3] += a1*b3;
            acc[2][0] += a2*b0; acc[2][1] += a2*b1; acc[2][2] += a2*b2; acc[2][3] += a2*b3;
            acc[3][0] += a3*b0; acc[3][1] += a3*b1; acc[3][2] += a3*b2; acc[3][3] += a3*b3;
        }
    }
#pragma unroll
    for (int r = 0; r < 4; ++r)
#pragma unroll
        for (int c = 0; c < 4; ++c)
            T[(row0 + ty*4 + r)*Mm + col0 + tx*4 + c] = acc[r][c];
}

// ---------------- gather + max + bias + relu ----------------
__global__ void maxrelu_kernel(const float* __restrict__ T, const int* __restrict__ idx,
                               const float* __restrict__ bias, float* __restrict__ out,
                               int O) {
    const int i = blockIdx.x;
    const int o = threadIdx.x;
    const int M2 = 2 * O;
    __shared__ int sidx[KNN];
    if (o < KNN) sidx[o] = idx[i*KNN + o];
    __syncthreads();
    float m = -INFINITY;
#pragma unroll
    for (int k = 0; k < KNN; ++k) {
        m = fmaxf(m, T[sidx[k]*M2 + O + o]);
    }
    const float base = T[i*M2 + o] + bias[o];
    out[i*O + o] = fmaxf(base + m, 0.0f);
}

extern "C" void kernel_launch(void* const* d_in, const int* in_sizes, int n_in,
                              void* d_out, int out_size, void* d_ws, size_t ws_size,
                              hipStream_t stream) {
    const float* x  = (const float*)d_in[0];
    const float* W0 = (const float*)d_in[1];
    const float* b0 = (const float*)d_in[2];
    const float* W1 = (const float*)d_in[3];
    const float* b1 = (const float*)d_in[4];
    const float* W2 = (const float*)d_in[5];
    const float* b2 = (const float*)d_in[6];
    float* out = (float*)d_out;
    char*  ws  = (char*)d_ws;

    // workspace layout (16B aligned offsets), total ~22 MB
    int*   idx  = (int*)(ws + 0);                 // 8192*20*4   = 655360
    float* Wc0  = (float*)(ws + 655360);          // 384*4       = 1536
    float* Wc1  = (float*)(ws + 656896);          // 16384*4     = 65536
    float* Wc2  = (float*)(ws + 722432);          // 65536*4     = 262144
    float* bufA = (float*)(ws + 984576);          // 8192*512*4  = 16777216
    float* bufB = (float*)(ws + 17761792);        // 8192*128*4  = 4194304
    // xq aliases bufA: knn finishes before gemm0 overwrites it (same stream)
    float4* xq  = (float4*)bufA;

    // KNN graph (shared by all 3 layers)
    prep_xq<<<32, 256, 0, stream>>>(x, xq);
    knn_kernel<<<NPTS / QPB, 256, 0, stream>>>(xq, idx);

    // weight restructure: Wc = [Wa - Wb ; Wb]
    prep_w<<<1, 256, 0, stream>>>(W0, Wc0, 64, 3);
    prep_w<<<32, 256, 0, stream>>>(W1, Wc1, 128, 64);
    prep_w<<<128, 256, 0, stream>>>(W2, Wc2, 256, 128);

    // layer 0: x(8192x3) -> t0(8192x128) -> h0(8192x64)
    gemm0_kernel<<<NPTS, 128, 0, stream>>>(x, Wc0, bufA);
    maxrelu_kernel<<<NPTS, 64, 0, stream>>>(bufA, idx, b0, bufB, 64);

    // layer 1: h0(8192x64) -> t1(8192x256) -> h1(8192x128)
    gemm_nt<<<dim3(128, 4), 256, 0, stream>>>(bufB, Wc1, bufA, 64, 256);
    maxrelu_kernel<<<NPTS, 128, 0, stream>>>(bufA, idx, b1, bufB, 128);

    // layer 2: h1(8192x128) -> t2(8192x512) -> out(8192x256)
    gemm_nt<<<dim3(128, 8), 256, 0, stream>>>(bufB, Wc2, bufA, 128, 512);
    maxrelu_kernel<<<NPTS, 256, 0, stream>>>(bufA, idx, b2, out, 256);
}

// Round 3
// 166.978 us; speedup vs baseline: 3.1605x; 2.3621x over previous
//
#include <hip/hip_runtime.h>
#include <math.h>

#define NPTS 8192
#define KNN  20

// ---------------- preprocess: xq[i] = (x,y,z, 0) ----------------
__global__ void prep_xq(const float* __restrict__ x, float4* __restrict__ xq) {
    const int i = blockIdx.x * 256 + threadIdx.x;
    if (i < NPTS) {
        xq[i] = make_float4(x[3*i+0], x[3*i+1], x[3*i+2], 0.0f);
    }
}

// 64-lane bitonic sort, ascending by lane. Keys d, payload ji.
__device__ __forceinline__ void bitonic64(float& d, int& ji, int lane) {
#pragma unroll
    for (int k = 2; k <= 64; k <<= 1) {
#pragma unroll
        for (int j = k >> 1; j > 0; j >>= 1) {
            const float od = __shfl_xor(d, j);
            const int   oi = __shfl_xor(ji, j);
            const bool up      = ((lane & k) == 0);
            const bool lower   = ((lane & j) == 0);
            const bool takeMin = (up == lower);
            const bool sw = takeMin ? (od < d) : (od > d);
            d  = sw ? od : d;
            ji = sw ? oi : ji;
        }
    }
}

// parallel sorted-insert of uniform (dc, jc) into the lane-distributed list
// (lanes 0..19 hold ascending list; lanes >=20 hold garbage, never read).
__device__ __forceinline__ void insert20(float& ld, int& lj, float dc, int jc, int lane) {
    const float pd = __shfl_up(ld, 1);
    const int   pj = __shfl_up(lj, 1);
    const bool keep = (ld <= dc);
    const bool here = (lane == 0) || (pd <= dc);
    ld = keep ? ld : (here ? dc : pd);
    lj = keep ? lj : (here ? jc : pj);
}

// ---------------- KNN: top-20 nearest (excl. self) ----------------
// block 256 = 4 waves; each wave owns 2 queries -> 8 queries/block, 1024 blocks.
// Wave-shared sorted top-20 list per query in registers (lanes 0..19).
__global__ __launch_bounds__(256) void knn_kernel(const float4* __restrict__ xq,
                                                  int* __restrict__ idx_out) {
    const int lane = threadIdx.x & 63;
    const int wv   = threadIdx.x >> 6;
    const int q0   = blockIdx.x * 8 + wv * 2;
    const int q1   = q0 + 1;

    const float4 p0 = xq[q0];
    const float4 p1 = xq[q1];

    // ---- batch 0 (candidates j = 0..63): bitonic init of both lists ----
    const float4 pc0 = xq[lane];
    float ax = p0.x - pc0.x, ay = p0.y - pc0.y, az = p0.z - pc0.z;
    float ld0 = ax*ax + ay*ay + az*az;
    float bx = p1.x - pc0.x, by = p1.y - pc0.y, bz = p1.z - pc0.z;
    float ld1 = bx*bx + by*by + bz*bz;
    if (lane == q0) ld0 = INFINITY;
    if (lane == q1) ld1 = INFINITY;
    int lj0 = lane, lj1 = lane;
    bitonic64(ld0, lj0, lane);
    bitonic64(ld1, lj1, lane);
    float cm0 = __shfl(ld0, KNN - 1);
    float cm1 = __shfl(ld1, KNN - 1);

    // ---- batches 1..127 ----
    for (int jj = 1; jj < NPTS / 64; ++jj) {
        const int jbase = jj * 64;
        const int j = jbase + lane;
        const float4 pc = xq[j];
        ax = p0.x - pc.x; ay = p0.y - pc.y; az = p0.z - pc.z;
        float d0 = ax*ax + ay*ay + az*az;
        bx = p1.x - pc.x; by = p1.y - pc.y; bz = p1.z - pc.z;
        float d1 = bx*bx + by*by + bz*bz;
        if (j == q0) d0 = INFINITY;
        if (j == q1) d1 = INFINITY;

        unsigned long long m0 = __ballot(d0 < cm0);
        unsigned long long m1 = __ballot(d1 < cm1);
        while (m0) {
            const int s = __ffsll(m0) - 1;
            m0 &= (m0 - 1);
            const float dc = __shfl(d0, s);
            if (dc < cm0) {
                insert20(ld0, lj0, dc, jbase + s, lane);
                cm0 = __shfl(ld0, KNN - 1);
            }
        }
        while (m1) {
            const int s = __ffsll(m1) - 1;
            m1 &= (m1 - 1);
            const float dc = __shfl(d1, s);
            if (dc < cm1) {
                insert20(ld1, lj1, dc, jbase + s, lane);
                cm1 = __shfl(ld1, KNN - 1);
            }
        }
    }

    if (lane < KNN) {
        idx_out[q0 * KNN + lane] = lj0;
        idx_out[q1 * KNN + lane] = lj1;
    }
}

// ---------------- weight prep: Wc = [Wa - Wb ; Wb], rows x C ----------------
__global__ void prep_w(const float* __restrict__ W, float* __restrict__ Wc,
                       int O, int C) {
    const int tid = blockIdx.x * blockDim.x + threadIdx.x;
    if (tid >= O * C) return;
    const int o = tid / C, k = tid % C;
    const float wa = W[o*2*C + k];
    const float wb = W[o*2*C + C + k];
    Wc[o*C + k]       = wa - wb;   // base part
    Wc[(O + o)*C + k] = wb;        // u part
}

// ---------------- layer0 GEMM: K=3 special case ----------------
__global__ __launch_bounds__(128) void gemm0_kernel(const float* __restrict__ x,
                                                    const float* __restrict__ Wc,
                                                    float* __restrict__ T) {
    __shared__ float sw[384];
    const int t = threadIdx.x;
    sw[t]       = Wc[t];
    sw[t + 128] = Wc[t + 128];
    sw[t + 256] = Wc[t + 256];
    __syncthreads();
    const int n = blockIdx.x;
    const float x0 = x[3*n+0], x1 = x[3*n+1], x2 = x[3*n+2];
    T[n*128 + t] = x0*sw[3*t+0] + x1*sw[3*t+1] + x2*sw[3*t+2];
}

// ---------------- generic fp32 GEMM: T = H (NxK) * Wc^T (MxK) ----------------
// 64x64 tile, 256 threads, 4x4 per thread. K % 16 == 0.
__global__ __launch_bounds__(256) void gemm_nt(const float* __restrict__ H,
                                               const float* __restrict__ W,
                                               float* __restrict__ T,
                                               int Kk, int Mm) {
    __shared__ float sH[64][17];
    __shared__ float sW[64][17];
    const int tx = threadIdx.x & 15;
    const int ty = threadIdx.x >> 4;
    const int row0 = blockIdx.x * 64;
    const int col0 = blockIdx.y * 64;
    float acc[4][4] = {{0.f}};
    const int l  = threadIdx.x * 4;
    const int lr = l >> 4;       // 0..63
    const int lc = l & 15;       // 0,4,8,12

    for (int k0 = 0; k0 < Kk; k0 += 16) {
        const float4 hv = *reinterpret_cast<const float4*>(&H[(row0+lr)*Kk + k0 + lc]);
        const float4 wv = *reinterpret_cast<const float4*>(&W[(col0+lr)*Kk + k0 + lc]);
        __syncthreads();   // protect previous iter's reads
        sH[lr][lc+0] = hv.x; sH[lr][lc+1] = hv.y; sH[lr][lc+2] = hv.z; sH[lr][lc+3] = hv.w;
        sW[lr][lc+0] = wv.x; sW[lr][lc+1] = wv.y; sW[lr][lc+2] = wv.z; sW[lr][lc+3] = wv.w;
        __syncthreads();
#pragma unroll
        for (int kk = 0; kk < 16; ++kk) {
            float a0 = sH[ty*4+0][kk], a1 = sH[ty*4+1][kk];
            float a2 = sH[ty*4+2][kk], a3 = sH[ty*4+3][kk];
            float b0 = sW[tx*4+0][kk], b1 = sW[tx*4+1][kk];
            float b2 = sW[tx*4+2][kk], b3 = sW[tx*4+3][kk];
            acc[0][0] += a0*b0; acc[0][1] += a0*b1; acc[0][2] += a0*b2; acc[0][3] += a0*b3;
            acc[1][0] += a1*b0; acc[1][1] += a1*b1; acc[1][2] += a1*b2; acc[1][3] += a1*b3;
            acc[2][0] += a2*b0; acc[2][1] += a2*b1; acc[2][2] += a2*b2; acc[2][3] += a2*b3;
            acc[3][0] += a3*b0; acc[3][1] += a3*b1; acc[3][2] += a3*b2; acc[3][3] += a3*b3;
        }
    }
#pragma unroll
    for (int r = 0; r < 4; ++r)
#pragma unroll
        for (int c = 0; c < 4; ++c)
            T[(row0 + ty*4 + r)*Mm + col0 + tx*4 + c] = acc[r][c];
}

// ---------------- gather + max + bias + relu ----------------
__global__ void maxrelu_kernel(const float* __restrict__ T, const int* __restrict__ idx,
                               const float* __restrict__ bias, float* __restrict__ out,
                               int O) {
    const int i = blockIdx.x;
    const int o = threadIdx.x;
    const int M2 = 2 * O;
    __shared__ int sidx[KNN];
    if (o < KNN) sidx[o] = idx[i*KNN + o];
    __syncthreads();
    float m = -INFINITY;
#pragma unroll
    for (int k = 0; k < KNN; ++k) {
        m = fmaxf(m, T[sidx[k]*M2 + O + o]);
    }
    const float base = T[i*M2 + o] + bias[o];
    out[i*O + o] = fmaxf(base + m, 0.0f);
}

extern "C" void kernel_launch(void* const* d_in, const int* in_sizes, int n_in,
                              void* d_out, int out_size, void* d_ws, size_t ws_size,
                              hipStream_t stream) {
    const float* x  = (const float*)d_in[0];
    const float* W0 = (const float*)d_in[1];
    const float* b0 = (const float*)d_in[2];
    const float* W1 = (const float*)d_in[3];
    const float* b1 = (const float*)d_in[4];
    const float* W2 = (const float*)d_in[5];
    const float* b2 = (const float*)d_in[6];
    float* out = (float*)d_out;
    char*  ws  = (char*)d_ws;

    // workspace layout (16B aligned offsets), total ~22 MB
    int*   idx  = (int*)(ws + 0);                 // 8192*20*4   = 655360
    float* Wc0  = (float*)(ws + 655360);          // 384*4       = 1536
    float* Wc1  = (float*)(ws + 656896);          // 16384*4     = 65536
    float* Wc2  = (float*)(ws + 722432);          // 65536*4     = 262144
    float* bufA = (float*)(ws + 984576);          // 8192*512*4  = 16777216
    float* bufB = (float*)(ws + 17761792);        // 8192*128*4  = 4194304
    // xq aliases bufA: knn finishes before gemm0 overwrites it (same stream)
    float4* xq  = (float4*)bufA;

    // KNN graph (shared by all 3 layers)
    prep_xq<<<32, 256, 0, stream>>>(x, xq);
    knn_kernel<<<NPTS / 8, 256, 0, stream>>>(xq, idx);

    // weight restructure: Wc = [Wa - Wb ; Wb]
    prep_w<<<1, 256, 0, stream>>>(W0, Wc0, 64, 3);
    prep_w<<<32, 256, 0, stream>>>(W1, Wc1, 128, 64);
    prep_w<<<128, 256, 0, stream>>>(W2, Wc2, 256, 128);

    // layer 0: x(8192x3) -> t0(8192x128) -> h0(8192x64)
    gemm0_kernel<<<NPTS, 128, 0, stream>>>(x, Wc0, bufA);
    maxrelu_kernel<<<NPTS, 64, 0, stream>>>(bufA, idx, b0, bufB, 64);

    // layer 1: h0(8192x64) -> t1(8192x256) -> h1(8192x128)
    gemm_nt<<<dim3(128, 4), 256, 0, stream>>>(bufB, Wc1, bufA, 64, 256);
    maxrelu_kernel<<<NPTS, 128, 0, stream>>>(bufA, idx, b1, bufB, 128);

    // layer 2: h1(8192x128) -> t2(8192x512) -> out(8192x256)
    gemm_nt<<<dim3(128, 8), 256, 0, stream>>>(bufB, Wc2, bufA, 128, 512);
    maxrelu_kernel<<<NPTS, 256, 0, stream>>>(bufA, idx, b2, out, 256);
}

// Round 4
// 148.168 us; speedup vs baseline: 3.5618x; 1.1270x over previous
//
#include <hip/hip_runtime.h>
#include <math.h>

#define NPTS 8192
#define KNN  20
#define CHUNK 1024                 // knn: candidates staged per LDS chunk
#define NCHUNK (NPTS / CHUNK)      // 8

// 64-lane bitonic sort, ascending by lane. Keys d, payload ji.
__device__ __forceinline__ void bitonic64(float& d, int& ji, int lane) {
#pragma unroll
    for (int k = 2; k <= 64; k <<= 1) {
#pragma unroll
        for (int j = k >> 1; j > 0; j >>= 1) {
            const float od = __shfl_xor(d, j);
            const int   oi = __shfl_xor(ji, j);
            const bool up      = ((lane & k) == 0);
            const bool lower   = ((lane & j) == 0);
            const bool takeMin = (up == lower);
            const bool sw = takeMin ? (od < d) : (od > d);
            d  = sw ? od : d;
            ji = sw ? oi : ji;
        }
    }
}

// parallel sorted-insert of wave-uniform (dc, jc) into lane-distributed ascending list
__device__ __forceinline__ void insert20(float& ld, int& lj, float dc, int jc, int lane) {
    const float pd = __shfl_up(ld, 1);
    const int   pj = __shfl_up(lj, 1);
    const bool keep = (ld <= dc);
    const bool here = (lane == 0) || (pd <= dc);
    ld = keep ? ld : (here ? dc : pd);
    lj = keep ? lj : (here ? jc : pj);
}

// ---------------- KNN: top-20 nearest (excl. self) ----------------
// 1 query per wave, 4 waves/block, 2048 blocks (100% occupancy cap).
// Candidates staged through LDS in 16 KB chunks (4x L2 traffic reduction).
// Lazy threshold: insert ALL ballot hits vs stale cm (correct: stale cm >= true
// cm, so every true top-20 beats it; extras are auto-dropped by sorted insert),
// refresh cm once per eventful batch.
__global__ __launch_bounds__(256) void knn_kernel(const float4* __restrict__ xq,
                                                  int* __restrict__ idx_out) {
    __shared__ float4 sxq[CHUNK];
    const int lane = threadIdx.x & 63;
    const int wv   = threadIdx.x >> 6;
    const int q    = blockIdx.x * 4 + wv;

    const float4 p = xq[q];

    float ld = INFINITY;
    int   lj = -1;
    float cm = INFINITY;

    for (int c = 0; c < NCHUNK; ++c) {
        __syncthreads();   // protect previous chunk's reads
#pragma unroll
        for (int u = 0; u < CHUNK / 256; ++u)
            sxq[u * 256 + threadIdx.x] = xq[c * CHUNK + u * 256 + threadIdx.x];
        __syncthreads();

        int bstart = 0;
        if (c == 0) {
            // init both: bitonic-sort first 64 candidates
            const float4 pc = sxq[lane];
            const float dx = p.x - pc.x, dy = p.y - pc.y, dz = p.z - pc.z;
            float d = dx*dx + dy*dy + dz*dz;
            if (lane == q) d = INFINITY;   // self (only possible when q < 64)
            ld = d; lj = lane;
            bitonic64(ld, lj, lane);
            cm = __shfl(ld, KNN - 1);
            bstart = 1;
        }
        for (int b = bstart; b < CHUNK / 64; ++b) {
            const int jbase = c * CHUNK + b * 64;
            const float4 pc = sxq[b * 64 + lane];
            const float dx = p.x - pc.x, dy = p.y - pc.y, dz = p.z - pc.z;
            float d = dx*dx + dy*dy + dz*dz;
            if (jbase + lane == q) d = INFINITY;

            unsigned long long m = __ballot(d < cm);
            if (m) {
                do {
                    const int s = __ffsll(m) - 1;
                    m &= (m - 1);
                    const float dc = __shfl(d, s);
                    insert20(ld, lj, dc, jbase + s, lane);
                } while (m);
                cm = __shfl(ld, KNN - 1);
            }
        }
    }

    if (lane < KNN) idx_out[q * KNN + lane] = lj;
}

// ---------------- fused prep: xq + Wc0 + Wc1 + Wc2 ----------------
// Wc = [Wa - Wb ; Wb] (2O x C), from W (O x 2C)
__device__ __forceinline__ void prep_w_elem(const float* __restrict__ W,
                                            float* __restrict__ Wc,
                                            int tid, int O, int C) {
    const int o = tid / C, k = tid % C;
    const float wa = W[o*2*C + k];
    const float wb = W[o*2*C + C + k];
    Wc[o*C + k]       = wa - wb;
    Wc[(O + o)*C + k] = wb;
}

__global__ void prep_all(const float* __restrict__ x,
                         const float* __restrict__ W0,
                         const float* __restrict__ W1,
                         const float* __restrict__ W2,
                         float4* __restrict__ xq,
                         float* __restrict__ Wc0,
                         float* __restrict__ Wc1,
                         float* __restrict__ Wc2) {
    const int bid = blockIdx.x;
    const int t = threadIdx.x;
    if (bid < 32) {                       // xq: 8192 pts
        const int i = bid * 256 + t;
        xq[i] = make_float4(x[3*i+0], x[3*i+1], x[3*i+2], 0.0f);
    } else if (bid == 32) {               // Wc0: 64x3 = 192 elems
        if (t < 192) prep_w_elem(W0, Wc0, t, 64, 3);
    } else if (bid < 65) {                // Wc1: 128x64 = 8192 elems, 32 blocks
        prep_w_elem(W1, Wc1, (bid - 33) * 256 + t, 128, 64);
    } else {                              // Wc2: 256x128 = 32768 elems, 128 blocks
        prep_w_elem(W2, Wc2, (bid - 65) * 256 + t, 256, 128);
    }
}

// ---------------- layer0 GEMM: K=3 special case ----------------
__global__ __launch_bounds__(128) void gemm0_kernel(const float* __restrict__ x,
                                                    const float* __restrict__ Wc,
                                                    float* __restrict__ T) {
    __shared__ float sw[384];
    const int t = threadIdx.x;
    sw[t]       = Wc[t];
    sw[t + 128] = Wc[t + 128];
    sw[t + 256] = Wc[t + 256];
    __syncthreads();
    const int n = blockIdx.x;
    const float x0 = x[3*n+0], x1 = x[3*n+1], x2 = x[3*n+2];
    T[n*128 + t] = x0*sw[3*t+0] + x1*sw[3*t+1] + x2*sw[3*t+2];
}

// ---------------- fp32 GEMM: T = H (NxK) * W^T (MxK) ----------------
// 128x64 tile, 256 threads, 8x4 per thread (row blocks rg*4 and 64+rg*4).
// K-major LDS (sH[k][row]) -> ds_read_b128 fragments, 2-way bank max (free).
#define BK 16
__global__ __launch_bounds__(256) void gemm_nt(const float* __restrict__ H,
                                               const float* __restrict__ W,
                                               float* __restrict__ T,
                                               int Kk, int Mm) {
    __shared__ float sH[BK][132];   // 128 rows + pad 4 (keeps 16B align, spreads banks)
    __shared__ float sW[BK][68];    // 64 cols + pad 4
    const int t  = threadIdx.x;
    const int rg = t & 15;          // row group
    const int cg = t >> 4;          // col group (0..15)
    const int row0 = blockIdx.x * 128;
    const int col0 = blockIdx.y * 64;

    const int ar = t >> 2;          // staging row 0..63
    const int ac = t & 3;           // staging k-chunk

    float acc[8][4];
#pragma unroll
    for (int r = 0; r < 8; ++r)
#pragma unroll
        for (int c = 0; c < 4; ++c) acc[r][c] = 0.0f;

    for (int k0 = 0; k0 < Kk; k0 += BK) {
        const float4 ha = *reinterpret_cast<const float4*>(&H[(row0 + ar)      * Kk + k0 + ac*4]);
        const float4 hb = *reinterpret_cast<const float4*>(&H[(row0 + 64 + ar) * Kk + k0 + ac*4]);
        const float4 wa = *reinterpret_cast<const float4*>(&W[(col0 + ar)      * Kk + k0 + ac*4]);
        __syncthreads();   // protect previous iter's reads
        sH[ac*4+0][ar]    = ha.x; sH[ac*4+1][ar]    = ha.y; sH[ac*4+2][ar]    = ha.z; sH[ac*4+3][ar]    = ha.w;
        sH[ac*4+0][64+ar] = hb.x; sH[ac*4+1][64+ar] = hb.y; sH[ac*4+2][64+ar] = hb.z; sH[ac*4+3][64+ar] = hb.w;
        sW[ac*4+0][ar]    = wa.x; sW[ac*4+1][ar]    = wa.y; sW[ac*4+2][ar]    = wa.z; sW[ac*4+3][ar]    = wa.w;
        __syncthreads();
#pragma unroll
        for (int kk = 0; kk < BK; ++kk) {
            const float4 a0 = *reinterpret_cast<const float4*>(&sH[kk][rg*4]);
            const float4 a1 = *reinterpret_cast<const float4*>(&sH[kk][64 + rg*4]);
            const float4 bv = *reinterpret_cast<const float4*>(&sW[kk][cg*4]);
            const float arr[8] = {a0.x, a0.y, a0.z, a0.w, a1.x, a1.y, a1.z, a1.w};
            const float bb[4]  = {bv.x, bv.y, bv.z, bv.w};
#pragma unroll
            for (int r = 0; r < 8; ++r)
#pragma unroll
                for (int c = 0; c < 4; ++c)
                    acc[r][c] = fmaf(arr[r], bb[c], acc[r][c]);
        }
    }
#pragma unroll
    for (int r = 0; r < 8; ++r) {
        const int row = (r < 4) ? (rg*4 + r) : (64 + rg*4 + (r - 4));
        *reinterpret_cast<float4*>(&T[(row0 + row)*Mm + col0 + cg*4]) =
            make_float4(acc[r][0], acc[r][1], acc[r][2], acc[r][3]);
    }
}

// ---------------- gather + max + bias + relu ----------------
__global__ void maxrelu_kernel(const float* __restrict__ T, const int* __restrict__ idx,
                               const float* __restrict__ bias, float* __restrict__ out,
                               int O) {
    const int i = blockIdx.x;
    const int o = threadIdx.x;
    const int M2 = 2 * O;
    __shared__ int sidx[KNN];
    if (o < KNN) sidx[o] = idx[i*KNN + o];
    __syncthreads();
    float m = -INFINITY;
#pragma unroll
    for (int k = 0; k < KNN; ++k) {
        m = fmaxf(m, T[sidx[k]*M2 + O + o]);
    }
    const float base = T[i*M2 + o] + bias[o];
    out[i*O + o] = fmaxf(base + m, 0.0f);
}

extern "C" void kernel_launch(void* const* d_in, const int* in_sizes, int n_in,
                              void* d_out, int out_size, void* d_ws, size_t ws_size,
                              hipStream_t stream) {
    const float* x  = (const float*)d_in[0];
    const float* W0 = (const float*)d_in[1];
    const float* b0 = (const float*)d_in[2];
    const float* W1 = (const float*)d_in[3];
    const float* b1 = (const float*)d_in[4];
    const float* W2 = (const float*)d_in[5];
    const float* b2 = (const float*)d_in[6];
    float* out = (float*)d_out;
    char*  ws  = (char*)d_ws;

    // workspace layout (16B aligned offsets), total ~22 MB
    int*   idx  = (int*)(ws + 0);                 // 8192*20*4   = 655360
    float* Wc0  = (float*)(ws + 655360);          // 384*4       = 1536
    float* Wc1  = (float*)(ws + 656896);          // 16384*4     = 65536
    float* Wc2  = (float*)(ws + 722432);          // 65536*4     = 262144
    float* bufA = (float*)(ws + 984576);          // 8192*512*4  = 16777216
    float* bufB = (float*)(ws + 17761792);        // 8192*128*4  = 4194304
    // xq aliases bufA: knn finishes before gemm0 overwrites it (same stream)
    float4* xq  = (float4*)bufA;

    // fused prep: xq + all weight restructures (1 launch)
    prep_all<<<193, 256, 0, stream>>>(x, W0, W1, W2, xq, Wc0, Wc1, Wc2);

    // KNN graph (shared by all 3 layers)
    knn_kernel<<<NPTS / 4, 256, 0, stream>>>(xq, idx);

    // layer 0: x(8192x3) -> t0(8192x128) -> h0(8192x64)
    gemm0_kernel<<<NPTS, 128, 0, stream>>>(x, Wc0, bufA);
    maxrelu_kernel<<<NPTS, 64, 0, stream>>>(bufA, idx, b0, bufB, 64);

    // layer 1: h0(8192x64) -> t1(8192x256) -> h1(8192x128)
    gemm_nt<<<dim3(64, 4), 256, 0, stream>>>(bufB, Wc1, bufA, 64, 256);
    maxrelu_kernel<<<NPTS, 128, 0, stream>>>(bufA, idx, b1, bufB, 128);

    // layer 2: h1(8192x128) -> t2(8192x512) -> out(8192x256)
    gemm_nt<<<dim3(64, 8), 256, 0, stream>>>(bufB, Wc2, bufA, 128, 512);
    maxrelu_kernel<<<NPTS, 256, 0, stream>>>(bufA, idx, b2, out, 256);
}

// Round 5
// 145.860 us; speedup vs baseline: 3.6181x; 1.0158x over previous
//
#include <hip/hip_runtime.h>
#include <math.h>

#define NPTS 8192
#define KNN  20
#define CHUNK 1024                 // knn: candidates staged per LDS chunk
#define NCHUNK (NPTS / CHUNK)      // 8

// 64-lane bitonic sort, ascending by lane. Keys d, payload ji.
__device__ __forceinline__ void bitonic64(float& d, int& ji, int lane) {
#pragma unroll
    for (int k = 2; k <= 64; k <<= 1) {
#pragma unroll
        for (int j = k >> 1; j > 0; j >>= 1) {
            const float od = __shfl_xor(d, j);
            const int   oi = __shfl_xor(ji, j);
            const bool up      = ((lane & k) == 0);
            const bool lower   = ((lane & j) == 0);
            const bool takeMin = (up == lower);
            const bool sw = takeMin ? (od < d) : (od > d);
            d  = sw ? od : d;
            ji = sw ? oi : ji;
        }
    }
}

// clean a bitonic 64-sequence into ascending order (6 compare-exchange stages)
__device__ __forceinline__ void bitonic_clean64(float& d, int& ji, int lane) {
#pragma unroll
    for (int j = 32; j > 0; j >>= 1) {
        const float od = __shfl_xor(d, j);
        const int   oi = __shfl_xor(ji, j);
        const bool lower = ((lane & j) == 0);
        const bool sw = lower ? (od < d) : (od > d);
        d  = sw ? od : d;
        ji = sw ? oi : ji;
    }
}

// merge LDS hit-pool (cnt entries) into the resident sorted-64 list (ld,lj)
__device__ __forceinline__ void compact(float& ld, int& lj,
                                        const float* __restrict__ sd,
                                        const int* __restrict__ sj,
                                        int cnt, int lane) {
    __builtin_amdgcn_wave_barrier();          // order pool ds_writes before reads
    float bd = (lane < cnt) ? sd[lane] : INFINITY;
    int   bj = (lane < cnt) ? sj[lane] : -1;
    bitonic64(bd, bj, lane);
    // reverse B, elementwise min vs A -> bitonic sequence of the 64 smallest
    const float rd = __shfl(bd, 63 - lane);
    const int   rj = __shfl(bj, 63 - lane);
    const bool sw = rd < ld;
    float md = sw ? rd : ld;
    int   mj = sw ? rj : lj;
    bitonic_clean64(md, mj, lane);
    ld = md; lj = mj;
}

// ---------------- KNN: top-20 nearest (excl. self) ----------------
// 1 query/wave, 4 waves/block, 2048 blocks. Candidates staged via 16 KB LDS
// chunks. Resident top-64 (first 21 = top-21 incl. self) in lane registers,
// sorted ascending. Hits appended lane-PARALLEL to a 64-slot LDS pool
// (ballot + mbcnt prefix); pool merged via bitonic sort+clean on overflow.
// Self (d=0) is always lane 0 at the end -> output lanes 1..20.
__global__ __launch_bounds__(256) void knn_kernel(const float4* __restrict__ xq,
                                                  int* __restrict__ idx_out) {
    __shared__ float4 sxq[CHUNK];
    __shared__ float  sdp[4][64];
    __shared__ int    sjp[4][64];
    const int lane = threadIdx.x & 63;
    const int wv   = threadIdx.x >> 6;
    const int q    = blockIdx.x * 4 + wv;

    const float4 p = xq[q];
    float* sd = sdp[wv];
    int*   sj = sjp[wv];

    float ld = INFINITY;
    int   lj = -1;
    float cm = INFINITY;
    int   cnt = 0;

    for (int c = 0; c < NCHUNK; ++c) {
        __syncthreads();   // protect previous chunk's reads
#pragma unroll
        for (int u = 0; u < CHUNK / 256; ++u)
            sxq[u * 256 + threadIdx.x] = xq[c * CHUNK + u * 256 + threadIdx.x];
        __syncthreads();

        int bstart = 0;
        if (c == 0) {
            // init: bitonic-sort first 64 candidates (self included, d=0)
            const float4 pc = sxq[lane];
            const float dx = p.x - pc.x, dy = p.y - pc.y, dz = p.z - pc.z;
            ld = dx*dx + dy*dy + dz*dz;
            lj = lane;
            bitonic64(ld, lj, lane);
            cm = __shfl(ld, KNN);   // 21st entry = 20th excluding self
            bstart = 1;
        }
#pragma unroll 2
        for (int b = bstart; b < CHUNK / 64; ++b) {
            const int jbase = c * CHUNK + b * 64;
            const float4 pc = sxq[b * 64 + lane];
            const float dx = p.x - pc.x, dy = p.y - pc.y, dz = p.z - pc.z;
            const float d = dx*dx + dy*dy + dz*dz;
            const bool hit = d < cm;
            const unsigned long long m = __ballot(hit);
            if (m) {
                const int tot = __popcll(m);
                if (cnt + tot > 64) {
                    compact(ld, lj, sd, sj, cnt, lane);
                    cm = __shfl(ld, KNN);
                    cnt = 0;
                }
                const int below = __builtin_amdgcn_mbcnt_hi(
                    (unsigned)(m >> 32),
                    __builtin_amdgcn_mbcnt_lo((unsigned)m, 0));
                const int pos = cnt + below;
                if (hit) { sd[pos] = d; sj[pos] = jbase + lane; }
                cnt += tot;
            }
        }
    }
    if (cnt > 0) compact(ld, lj, sd, sj, cnt, lane);

    if (lane >= 1 && lane <= KNN) idx_out[q * KNN + lane - 1] = lj;
}

// ---------------- fused prep: xq + Wc0 + Wc1 + Wc2 ----------------
__device__ __forceinline__ void prep_w_elem(const float* __restrict__ W,
                                            float* __restrict__ Wc,
                                            int tid, int O, int C) {
    const int o = tid / C, k = tid % C;
    const float wa = W[o*2*C + k];
    const float wb = W[o*2*C + C + k];
    Wc[o*C + k]       = wa - wb;
    Wc[(O + o)*C + k] = wb;
}

__global__ void prep_all(const float* __restrict__ x,
                         const float* __restrict__ W0,
                         const float* __restrict__ W1,
                         const float* __restrict__ W2,
                         float4* __restrict__ xq,
                         float* __restrict__ Wc0,
                         float* __restrict__ Wc1,
                         float* __restrict__ Wc2) {
    const int bid = blockIdx.x;
    const int t = threadIdx.x;
    if (bid < 32) {
        const int i = bid * 256 + t;
        xq[i] = make_float4(x[3*i+0], x[3*i+1], x[3*i+2], 0.0f);
    } else if (bid == 32) {
        if (t < 192) prep_w_elem(W0, Wc0, t, 64, 3);
    } else if (bid < 65) {
        prep_w_elem(W1, Wc1, (bid - 33) * 256 + t, 128, 64);
    } else {
        prep_w_elem(W2, Wc2, (bid - 65) * 256 + t, 256, 128);
    }
}

// ---------------- layer0 GEMM: K=3 special case ----------------
__global__ __launch_bounds__(128) void gemm0_kernel(const float* __restrict__ x,
                                                    const float* __restrict__ Wc,
                                                    float* __restrict__ T) {
    __shared__ float sw[384];
    const int t = threadIdx.x;
    sw[t]       = Wc[t];
    sw[t + 128] = Wc[t + 128];
    sw[t + 256] = Wc[t + 256];
    __syncthreads();
    const int n = blockIdx.x;
    const float x0 = x[3*n+0], x1 = x[3*n+1], x2 = x[3*n+2];
    T[n*128 + t] = x0*sw[3*t+0] + x1*sw[3*t+1] + x2*sw[3*t+2];
}

// ---------------- fp32 GEMM: T = H (NxK) * W^T (MxK) ----------------
#define BK 16
__global__ __launch_bounds__(256) void gemm_nt(const float* __restrict__ H,
                                               const float* __restrict__ W,
                                               float* __restrict__ T,
                                               int Kk, int Mm) {
    __shared__ float sH[BK][132];
    __shared__ float sW[BK][68];
    const int t  = threadIdx.x;
    const int rg = t & 15;
    const int cg = t >> 4;
    const int row0 = blockIdx.x * 128;
    const int col0 = blockIdx.y * 64;

    const int ar = t >> 2;
    const int ac = t & 3;

    float acc[8][4];
#pragma unroll
    for (int r = 0; r < 8; ++r)
#pragma unroll
        for (int c = 0; c < 4; ++c) acc[r][c] = 0.0f;

    for (int k0 = 0; k0 < Kk; k0 += BK) {
        const float4 ha = *reinterpret_cast<const float4*>(&H[(row0 + ar)      * Kk + k0 + ac*4]);
        const float4 hb = *reinterpret_cast<const float4*>(&H[(row0 + 64 + ar) * Kk + k0 + ac*4]);
        const float4 wa = *reinterpret_cast<const float4*>(&W[(col0 + ar)      * Kk + k0 + ac*4]);
        __syncthreads();
        sH[ac*4+0][ar]    = ha.x; sH[ac*4+1][ar]    = ha.y; sH[ac*4+2][ar]    = ha.z; sH[ac*4+3][ar]    = ha.w;
        sH[ac*4+0][64+ar] = hb.x; sH[ac*4+1][64+ar] = hb.y; sH[ac*4+2][64+ar] = hb.z; sH[ac*4+3][64+ar] = hb.w;
        sW[ac*4+0][ar]    = wa.x; sW[ac*4+1][ar]    = wa.y; sW[ac*4+2][ar]    = wa.z; sW[ac*4+3][ar]    = wa.w;
        __syncthreads();
#pragma unroll
        for (int kk = 0; kk < BK; ++kk) {
            const float4 a0 = *reinterpret_cast<const float4*>(&sH[kk][rg*4]);
            const float4 a1 = *reinterpret_cast<const float4*>(&sH[kk][64 + rg*4]);
            const float4 bv = *reinterpret_cast<const float4*>(&sW[kk][cg*4]);
            const float arr[8] = {a0.x, a0.y, a0.z, a0.w, a1.x, a1.y, a1.z, a1.w};
            const float bb[4]  = {bv.x, bv.y, bv.z, bv.w};
#pragma unroll
            for (int r = 0; r < 8; ++r)
#pragma unroll
                for (int c = 0; c < 4; ++c)
                    acc[r][c] = fmaf(arr[r], bb[c], acc[r][c]);
        }
    }
#pragma unroll
    for (int r = 0; r < 8; ++r) {
        const int row = (r < 4) ? (rg*4 + r) : (64 + rg*4 + (r - 4));
        *reinterpret_cast<float4*>(&T[(row0 + row)*Mm + col0 + cg*4]) =
            make_float4(acc[r][0], acc[r][1], acc[r][2], acc[r][3]);
    }
}

// ---------------- gather + max + bias + relu ----------------
// 256 threads = (256/O) points per block; templated O for compile-time div.
template<int O>
__global__ __launch_bounds__(256) void maxrelu_kernel(const float* __restrict__ T,
                                                      const int* __restrict__ idx,
                                                      const float* __restrict__ bias,
                                                      float* __restrict__ out) {
    constexpr int PPB = 256 / O;
    constexpr int M2  = 2 * O;
    const int pi = threadIdx.x / O;               // point within block
    const int o  = threadIdx.x & (O - 1);
    const int i  = blockIdx.x * PPB + pi;
    __shared__ int sidx[PPB * KNN];
    if (threadIdx.x < PPB * KNN)
        sidx[threadIdx.x] = idx[blockIdx.x * PPB * KNN + threadIdx.x];
    __syncthreads();
    const int sb = pi * KNN;
    float m = -INFINITY;
#pragma unroll
    for (int k = 0; k < KNN; ++k)
        m = fmaxf(m, T[sidx[sb + k] * M2 + O + o]);
    const float base = T[i * M2 + o] + bias[o];
    out[i * O + o] = fmaxf(base + m, 0.0f);
}

extern "C" void kernel_launch(void* const* d_in, const int* in_sizes, int n_in,
                              void* d_out, int out_size, void* d_ws, size_t ws_size,
                              hipStream_t stream) {
    const float* x  = (const float*)d_in[0];
    const float* W0 = (const float*)d_in[1];
    const float* b0 = (const float*)d_in[2];
    const float* W1 = (const float*)d_in[3];
    const float* b1 = (const float*)d_in[4];
    const float* W2 = (const float*)d_in[5];
    const float* b2 = (const float*)d_in[6];
    float* out = (float*)d_out;
    char*  ws  = (char*)d_ws;

    int*   idx  = (int*)(ws + 0);                 // 8192*20*4   = 655360
    float* Wc0  = (float*)(ws + 655360);          // 384*4       = 1536
    float* Wc1  = (float*)(ws + 656896);          // 16384*4     = 65536
    float* Wc2  = (float*)(ws + 722432);          // 65536*4     = 262144
    float* bufA = (float*)(ws + 984576);          // 8192*512*4  = 16777216
    float* bufB = (float*)(ws + 17761792);        // 8192*128*4  = 4194304
    float4* xq  = (float4*)bufA;  // aliases bufA; knn done before gemm0 writes

    prep_all<<<193, 256, 0, stream>>>(x, W0, W1, W2, xq, Wc0, Wc1, Wc2);

    knn_kernel<<<NPTS / 4, 256, 0, stream>>>(xq, idx);

    gemm0_kernel<<<NPTS, 128, 0, stream>>>(x, Wc0, bufA);
    maxrelu_kernel<64><<<NPTS / 4, 256, 0, stream>>>(bufA, idx, b0, bufB);

    gemm_nt<<<dim3(64, 4), 256, 0, stream>>>(bufB, Wc1, bufA, 64, 256);
    maxrelu_kernel<128><<<NPTS / 2, 256, 0, stream>>>(bufA, idx, b1, bufB);

    gemm_nt<<<dim3(64, 8), 256, 0, stream>>>(bufB, Wc2, bufA, 128, 512);
    maxrelu_kernel<256><<<NPTS, 256, 0, stream>>>(bufA, idx, b2, out);
}